// Round 7
// baseline (138.794 us; speedup 1.0000x reference)
//
#include <hip/hip_runtime.h>
#include <math.h>

// Problem constants: V=50000, D=100, B=16, S=128, U=100, L=2
#define NB 16
#define SS 128
#define DD 100
#define KK 100
#define T_TILE 8
#define NTILES 16
#define NT 512           // 8 waves = 4 d-quarters (h) x 2 pos-groups (g)

__device__ __forceinline__ float dot4(const float4 a, const float4 b) {
  return a.x * b.x + a.y * b.y + a.z * b.z + a.w * b.w;
}

// exact /25 for arg < 43690*25 (we use < 2560)
__device__ __forceinline__ int div25(int x) { return (x * 10486) >> 18; }

// ---------------------------------------------------------------------------
// Stage one 100x100 matrix part (40,000B = 2560 granules of 16B) into LDS via
// global_load_lds. LDS dest is LINEAR; the global source is pre-swizzled so
// that the READ pattern (lane kp reads slot (u+3kp)%25 of rows 2kp,2kp+1)
// lands j_orig = u. Storage rule: row k, slot s holds element j=(s-3*(k>>1))%25.
// ---------------------------------------------------------------------------
__device__ __forceinline__ void stage_part(const float* __restrict__ gv,
                                           char* vs, int wid, int lane) {
#pragma unroll
  for (int ii = 0; ii < 5; ++ii) {
    const int i = wid + 8 * ii;          // 40 instrs over 8 waves
    const int L = (i << 6) + lane;       // dest granule
    const int k = div25(L);
    const int s = L - 25 * k;
    int t = s + 150 - 3 * (k >> 1);      // (s - 3*(k>>1)) mod 25, t in [3,174]
    t -= 25 * div25(t);
    const float* src = gv + k * DD + 4 * t;
    __builtin_amdgcn_global_load_lds(src, (float*)(vs + (i << 10)), 16, 0, 0);
  }
}

// ---------------------------------------------------------------------------
// One projection stage. MODE 0: complex x; MODE 1: real x.
// CM 1: out[p,k] = |Y|^2*iv          (-> xbR region, m1)
// CM 2: out[p,k] = |w0 Y(p)+w1 Y(p+1)|^2*iv   (-> xbI region, m2)
// CM 3: y3[p,k] = Y raw (float4 per k-pair) + invvnU  (-> xb as float2*)
// Lane owns k-pair (k0=2kp); wave (h,g): d-slice [O,O+nu) granules, positions
// 6g+e. V: LDS->VGPR once (both parts resident); x: LDS broadcast.
// Partials combined via partl (overlaid on the V staging buffer).
// ---------------------------------------------------------------------------
template<int MODE, int CM>
__device__ __forceinline__ void do_stage(
    const float* __restrict__ gvr, const float* __restrict__ gvi,
    char* vs, const float* __restrict__ xR, const float* __restrict__ xI,
    float* __restrict__ outp, float* __restrict__ invvnU,
    const float* __restrict__ es, const float* __restrict__ sc,
    int nu, int O, int pmaxF, int pmaxC,
    int wid, int lane, int h, int g, int kp, bool act, int t0)
{
  float4* partlp = (float4*)vs;                 // [4][11][50]
  float2* nrmhp  = (float2*)(vs + 35200);       // [4][50]
  float4 Vr0[7], Vr1[7], Vi0[7], Vi1[7];
  float n0 = 0.f, n1 = 0.f;

  const int s3 = 3 * kp;
  const int sb = (s3 - 25 * div25(s3)) + O;     // (3kp)%25 + O  (<= 43)

  // phase r: stage + fill regs
  stage_part(gvr, vs, wid, lane);
  __syncthreads();
#pragma unroll
  for (int U = 0; U < 7; ++U) if (U < nu) {
    int su = sb + U; if (su >= 25) su -= 25;
    const float4* pR = (const float4*)(vs + ((50 * kp + su) << 4));
    Vr0[U] = pR[0];
    Vr1[U] = pR[25];
    n0 += dot4(Vr0[U], Vr0[U]);
    n1 += dot4(Vr1[U], Vr1[U]);
  }
  __syncthreads();
  // phase i: stage + fill regs
  stage_part(gvi, vs, wid, lane);
  __syncthreads();
#pragma unroll
  for (int U = 0; U < 7; ++U) if (U < nu) {
    int su = sb + U; if (su >= 25) su -= 25;
    const float4* pR = (const float4*)(vs + ((50 * kp + su) << 4));
    Vi0[U] = pR[0];
    Vi1[U] = pR[25];
    n0 += dot4(Vi0[U], Vi0[U]);
    n1 += dot4(Vi1[U], Vi1[U]);
  }

  // FMA pass: x broadcast from LDS, V in regs
  float ar[6][2] = {{0}}, ai[6][2] = {{0}};
#pragma unroll
  for (int U = 0; U < 7; ++U) if (U < nu) {
    const int u = O + U;
#pragma unroll
    for (int e = 0; e < 6; ++e) {
      const int p = 6 * g + e;
      if (p <= pmaxF) {
        const float4 xr = *(const float4*)(xR + p * DD + 4 * u);
        if (MODE == 0) {
          const float4 xi = *(const float4*)(xI + p * DD + 4 * u);
          ar[e][0] += dot4(Vr0[U], xr) + dot4(Vi0[U], xi);
          ai[e][0] += dot4(Vr0[U], xi) - dot4(Vi0[U], xr);
          ar[e][1] += dot4(Vr1[U], xr) + dot4(Vi1[U], xi);
          ai[e][1] += dot4(Vr1[U], xi) - dot4(Vi1[U], xr);
        } else {
          ar[e][0] += dot4(Vr0[U], xr);
          ai[e][0] += dot4(Vi0[U], xr);
          ar[e][1] += dot4(Vr1[U], xr);
          ai[e][1] += dot4(Vi1[U], xr);
        }
      }
    }
  }
  __syncthreads();   // V consumed; vspace free for partials

  if (act) {
#pragma unroll
    for (int e = 0; e < 6; ++e) {
      const int p = 6 * g + e;
      if (p <= pmaxF)
        partlp[h * 550 + p * 50 + kp] =
            make_float4(ar[e][0], ai[e][0], ar[e][1], ai[e][1]);
    }
    if (g == 0) nrmhp[h * 50 + kp] = make_float2(n0, n1);
  }
  __syncthreads();

  // combine (h==0 waves)
  if (h == 0 && act) {
    const float2 q0 = nrmhp[kp], q1 = nrmhp[50 + kp],
                 q2 = nrmhp[100 + kp], q3 = nrmhp[150 + kp];
    const float iv0 = 1.f / (q0.x + q1.x + q2.x + q3.x);
    const float iv1 = 1.f / (q0.y + q1.y + q2.y + q3.y);
    const float iZ0 = 1.f / sc[0], iZ1 = 1.f / sc[1];
#pragma unroll
    for (int e = 0; e < 6; ++e) {
      const int p = 6 * g + e;
      if (p <= pmaxC) {
        float4 s = partlp[p * 50 + kp];
        {
          const float4 b1 = partlp[550 + p * 50 + kp];
          const float4 b2 = partlp[1100 + p * 50 + kp];
          const float4 b3 = partlp[1650 + p * 50 + kp];
          s.x += b1.x + b2.x + b3.x;  s.y += b1.y + b2.y + b3.y;
          s.z += b1.z + b2.z + b3.z;  s.w += b1.w + b2.w + b3.w;
        }
        if (CM == 1) {
          *(float2*)(outp + p * DD + 2 * kp) =
              make_float2((s.x * s.x + s.y * s.y) * iv0,
                          (s.z * s.z + s.w * s.w) * iv1);
        } else if (CM == 2) {
          float4 u4 = partlp[(p + 1) * 50 + kp];
          const float4 c1 = partlp[550 + (p + 1) * 50 + kp];
          const float4 c2 = partlp[1100 + (p + 1) * 50 + kp];
          const float4 c3 = partlp[1650 + (p + 1) * 50 + kp];
          u4.x += c1.x + c2.x + c3.x;  u4.y += c1.y + c2.y + c3.y;
          u4.z += c1.z + c2.z + c3.z;  u4.w += c1.w + c2.w + c3.w;
          const int t = t0 + p;
          const float w0 = es[t] * iZ0;
          const float w1 = es[t + 1] * iZ1;     // es zero-padded past SS
          const float r0 = w0 * s.x + w1 * u4.x, i0 = w0 * s.y + w1 * u4.y;
          const float r1 = w0 * s.z + w1 * u4.z, i1 = w0 * s.w + w1 * u4.w;
          *(float2*)(outp + p * DD + 2 * kp) =
              make_float2((r0 * r0 + i0 * i0) * iv0, (r1 * r1 + i1 * i1) * iv1);
        } else {
          *(float4*)((float2*)outp + p * DD + 2 * kp) = s;
        }
      }
    }
    if (CM == 3 && g == 0) { invvnU[2 * kp] = iv0; invvnU[2 * kp + 1] = iv1; }
  }
  __syncthreads();
}

// ---------------------------------------------------------------------------
// Per-batch norms/exp/softmax-denominators (ONCE, not per tile-block)
// ---------------------------------------------------------------------------
__global__ __launch_bounds__(512) void k_norm(
    const int* __restrict__ seq, const float* __restrict__ ampT,
    float* __restrict__ es_g, float* __restrict__ wnl_g, float* __restrict__ sc_g)
{
  __shared__ float esl[SS], wnll[SS], red2[2];
  const int b = blockIdx.x, tid = threadIdx.x;
  const int t = tid >> 2, qq = tid & 3;
  const int row = seq[b * SS + t];
  const float* ap = ampT + (long)row * DD;
  float s = 0.f;
#pragma unroll
  for (int i = 0; i < 7; ++i) {
    const int j = qq + 4 * i;
    if (j < 25) {
      const float4 a4 = *(const float4*)(ap + 4 * j);
      s += dot4(a4, a4);
    }
  }
  s += __shfl_xor(s, 1);
  s += __shfl_xor(s, 2);
  if (qq == 0) { const float n = sqrtf(s); wnll[t] = n; esl[t] = expf(n); }
  __syncthreads();
  if (tid < SS) {
    float v = esl[tid];
#pragma unroll
    for (int m = 32; m; m >>= 1) v += __shfl_xor(v, m);
    if ((tid & 63) == 0) red2[tid >> 6] = v;
  }
  __syncthreads();
  if (tid < SS) { es_g[b * SS + tid] = esl[tid]; wnl_g[b * SS + tid] = wnll[tid]; }
  if (tid == 0) {
    const float E = red2[0] + red2[1];
    sc_g[b * 4 + 0] = E;
    sc_g[b * 4 + 1] = E - esl[0] + 1.f;
    sc_g[b * 4 + 2] = E - esl[0] - esl[1] + 2.f;
  }
}

// ---------------------------------------------------------------------------
__global__ __launch_bounds__(NT) void k_fused(
    const int* __restrict__ seq,
    const float* __restrict__ ampT, const float* __restrict__ phT,
    const float* __restrict__ pkr, const float* __restrict__ pki,
    const float* __restrict__ mkr, const float* __restrict__ mki,
    const float* __restrict__ es_g, const float* __restrict__ wnl_g,
    const float* __restrict__ sc_g, float* __restrict__ partg)
{
  __shared__ __align__(16) char vspace[40960];  // V staging / partl+nrmh union
  __shared__ float xb[2200];                    // phi(r,i) -> m1,m2 -> y3
  __shared__ float es[SS + 8];
  __shared__ float wnl[SS];
  __shared__ float invvnU[KK];
  __shared__ float sc[3];

  const int tid  = threadIdx.x;
  const int lane = tid & 63;
  const int wid  = tid >> 6;      // 0..7
  const int h    = wid & 3;       // d-quarter
  const int g    = wid >> 2;      // pos-group (0..1)
  const bool act = lane < 50;
  const int kp   = act ? lane : 49;
  const int bt   = blockIdx.x;
  const int b    = bt >> 4;
  const int t0   = (bt & 15) * T_TILE;
  const int sb   = b * SS;
  const int O    = (h == 0) ? 0 : 7 + 6 * (h - 1);   // 0,7,13,19
  const int nu   = (h == 0) ? 7 : 6;

  float* xbR = xb;
  float* xbI = xb + 1100;

  // --- prologue: load per-batch norm state ---
  if (tid < SS) { es[tid] = es_g[sb + tid]; wnl[tid] = wnl_g[sb + tid]; }
  if (tid >= SS && tid < SS + 8) es[tid] = 0.f;
  if (tid < 3) sc[tid] = sc_g[(b << 2) + tid];
  __syncthreads();

  // --- phi = (amp/||amp||) e^{i phase} for the 11-position halo -> LDS ---
  for (int e2 = tid; e2 < 11 * DD; e2 += NT) {
    const int p = e2 / DD, d = e2 - p * DD;
    const int t = t0 + p;
    float pr = 0.f, pi = 0.f;
    if (t < SS) {
      const int row = seq[sb + t];
      const float a  = ampT[(long)row * DD + d];
      const float ph = phT[(long)row * DD + d];
      float sv, cv; sincosf(ph, &sv, &cv);
      const float an = a / wnl[t];
      pr = an * cv; pi = an * sv;
    }
    xbR[p * DD + d] = pr;
    xbI[p * DD + d] = pi;
  }
  __syncthreads();

  // --- stage 1: m1 = |<v0, phi>|^2 * iv  (complex x) ---
  do_stage<0, 1>(pkr, pki, vspace, xbR, xbI, xbR, invvnU, es, sc,
                 nu, O, 10, 10, wid, lane, h, g, kp, act, t0);
  // --- stage 2: m2 = |2-tap window of <v1, m1>|^2 * iv ---
  do_stage<1, 2>(pkr + DD * DD, pki + DD * DD, vspace, xbR, xbR, xbI, invvnU,
                 es, sc, nu, O, 10, 9, wid, lane, h, g, kp, act, t0);
  // --- stage 3: y3 = <u, m2> raw (+ invvnU) ---
  do_stage<1, 3>(mkr, mki, vspace, xbI, xbI, xb, invvnU, es, sc,
                 nu, O, 9, 9, wid, lane, h, g, kp, act, t0);

  // --- final: 3-tap window, |.|^2, * wn[t] * invvnU; sum over tile ---
  if (tid < KK) {
    const float2* y3f = (const float2*)xb;
    const int k = tid;
    const float iE = 1.f / sc[0], iZ1 = 1.f / sc[1], iZ2 = 1.f / sc[2];
    float acc = 0.f;
#pragma unroll
    for (int p = 0; p < T_TILE; ++p) {
      const int t = t0 + p;
      const float w0 = es[t] * iE;
      const float w1 = es[t + 1] * iZ1;
      const float w2 = es[t + 2] * iZ2;
      const float2 a = y3f[p * DD + k], bb = y3f[(p + 1) * DD + k],
                   c = y3f[(p + 2) * DD + k];
      const float qr = w0 * a.x + w1 * bb.x + w2 * c.x;
      const float qi = w0 * a.y + w1 * bb.y + w2 * c.y;
      acc += wnl[t] * (qr * qr + qi * qi);
    }
    partg[bt * KK + k] = acc * invvnU[k];
  }
}

// ---------------------------------------------------------------------------
__global__ __launch_bounds__(128) void k_out(
    const float* __restrict__ partg, const float* __restrict__ dw,
    const float* __restrict__ db, float* __restrict__ out)
{
  __shared__ float pr[KK];
  const int b = blockIdx.x, tid = threadIdx.x;
  if (tid < KK) {
    float s = 0.f;
#pragma unroll
    for (int q = 0; q < NTILES; ++q) s += partg[(b * NTILES + q) * KK + tid];
    pr[tid] = s;
  }
  __syncthreads();
  if (tid < 2) {
    float s = db[tid];
    for (int k = 0; k < KK; ++k) s += pr[k] * dw[k * 2 + tid];
    out[b * 2 + tid] = s;
  }
}

// ---------------------------------------------------------------------------
extern "C" void kernel_launch(void* const* d_in, const int* in_sizes, int n_in,
                              void* d_out, int out_size, void* d_ws, size_t ws_size,
                              hipStream_t stream) {
  const int*   seq  = (const int*)d_in[0];
  const float* ampT = (const float*)d_in[1];
  const float* phT  = (const float*)d_in[2];
  const float* pkr  = (const float*)d_in[3];
  const float* pki  = (const float*)d_in[4];
  const float* mkr  = (const float*)d_in[5];
  const float* mki  = (const float*)d_in[6];
  const float* dw   = (const float*)d_in[7];
  const float* db   = (const float*)d_in[8];
  float* out = (float*)d_out;

  float* ws    = (float*)d_ws;
  float* es_g  = ws;                 // [16][128]
  float* wnl_g = ws + 2048;          // [16][128]
  float* sc_g  = ws + 4096;          // [16][4]
  float* partg = ws + 4160;          // [256][100]

  k_norm <<<NB,          512, 0, stream>>>(seq, ampT, es_g, wnl_g, sc_g);
  k_fused<<<NB * NTILES, NT,  0, stream>>>(seq, ampT, phT, pkr, pki, mkr, mki,
                                           es_g, wnl_g, sc_g, partg);
  k_out  <<<NB,          128, 0, stream>>>(partg, dw, db, out);
}